// Round 9
// baseline (6971.164 us; speedup 1.0000x reference)
//
#include <hip/hip_runtime.h>
#include <cfloat>
#include <math.h>

#define N 512
typedef unsigned long long u64_t;

__device__ __forceinline__ u64_t map_f64(double x) {
    u64_t b = (u64_t)__double_as_longlong(x);
    return b ^ ((b >> 63) ? 0xFFFFFFFFFFFFFFFFull : 0x8000000000000000ull);
}
__device__ __forceinline__ double unmap_f64(u64_t b) {
    b ^= ((b >> 63) ? 0x8000000000000000ull : 0xFFFFFFFFFFFFFFFFull);
    return __longlong_as_double((long long)b);
}

// wave64 u64 min-reduce via DPP (VALU pipe). Valid result in lane 63.
// row_shr:1/2/4/8 reduce within 16-lane rows; row_bcast:15/31 merge rows.
// bound_ctrl=false + old=own value => lanes w/o source keep own (min identity).
__device__ __forceinline__ u64_t wave_min_key(u64_t key) {
    unsigned hi = (unsigned)(key >> 32), lo = (unsigned)key;
#define MIN_STAGE(CTRL)                                                        \
    {                                                                          \
        unsigned oh = (unsigned)__builtin_amdgcn_update_dpp((int)hi, (int)hi,  \
                                                            CTRL, 0xF, 0xF, false); \
        unsigned ol = (unsigned)__builtin_amdgcn_update_dpp((int)lo, (int)lo,  \
                                                            CTRL, 0xF, 0xF, false); \
        const u64_t o = ((u64_t)oh << 32) | ol;                                \
        const u64_t c = ((u64_t)hi << 32) | lo;                                \
        if (o < c) { hi = oh; lo = ol; }                                       \
    }
    MIN_STAGE(0x111) MIN_STAGE(0x112) MIN_STAGE(0x114) MIN_STAGE(0x118)
    MIN_STAGE(0x142) MIN_STAGE(0x143)
#undef MIN_STAGE
    return ((u64_t)hi << 32) | lo;
}

// 512 threads / 8 waves, thread t owns column t+1. Exact JV:
// column reduction + greedy tight match + LAPJV ARR warm start, then
// Dijkstra with DPP wave-reduce + 8-slot combine.
// key = [45b value | 9b col-1 | 10b p[col]] (truncation precedent: absmax 0).
// Ledger: R1 L2 cost matrix worse; R2 2nd ARR pass churns; R3 4-wave/2-col
// worse (confounded); R5/R6 single-wave 3100cy/iter; R7 f32 filter via LDS
// worse (+2 critical-path LDS reads). R4 base = 5643us, interval ~1050cy vs
// ~600cy chain model. R9 isolates the last unmeasured term: the 8-way
// SAME-ADDRESS LDS atomicMin combine (suspected ~300-450cy serialization that
// delays the pace-setting last wave). Swap: lane63 plain ds_write to
// dslot[par][wid] (contention-free) + B-phase broadcast read of 8 slots +
// 3-level min-tree (~50cy post-barrier). Min over the same 8 distinct keys
// => bit-identical winner sequence. Parity-2 is race-free with 1 barrier/iter
// (2 barriers between same-parity writes); no resets needed (plain overwrite,
// all 8 slots written every iteration before the barrier).
__global__ __launch_bounds__(512, 1) void tofu_solver(
    const float* __restrict__ dgm, const float* __restrict__ dgm_x,
    float* __restrict__ out)
{
#pragma clang fp contract(off)
    __shared__ double2 pt[N];
    __shared__ double  u_lds[N + 1];
    __shared__ int     p_lds[N + 1];
    __shared__ int     way_lds[N + 1];
    __shared__ int     claim[N + 1];
    __shared__ int     flist[4 * N + 32];
    __shared__ u64_t   dslot[2][8];     // Dijkstra combine slots (parity x wave)
    __shared__ u64_t   aslot[2], bslot[2];  // ARR slots (parity)
    __shared__ double  v1x;
    __shared__ double  red8[8];
    __shared__ int     nfree_s;

    const int tid  = threadIdx.x;       // 0..511
    const int col  = tid + 1;           // 1..512
    const int lane = tid & 63;
    const int wid  = tid >> 6;
    const float2* dgm2  = (const float2*)dgm;
    const float2* dgmx2 = (const float2*)dgm_x;

    // ---- stage points; own column's target point in registers ----
    {
        const float2 p2 = dgm2[tid];
        pt[tid] = make_double2((double)p2.x, (double)p2.y);
    }
    const float2 q2 = dgmx2[tid];
    const double xb = (double)q2.x, xd = (double)q2.y;
    u_lds[col] = 0.0; p_lds[col] = 0; way_lds[col] = 0; claim[col] = 0x7fffffff;
    if (tid == 0) {
        u_lds[0] = 0.0; p_lds[0] = 0; way_lds[0] = 0; claim[0] = 0x7fffffff;
        aslot[0] = aslot[1] = ~0ull; bslot[0] = bslot[1] = ~0ull;
    }
    __syncthreads();

    // ---- column reduction: argmin over squared dist (sqrt monotone => same v) ----
    double v_j; int amin;
    {
        double vsq = DBL_MAX; amin = 1;
        for (int i = 0; i < N; ++i) {
            const double2 rp = pt[i];                 // broadcast b128
            const double db = rp.x - xb, dd = rp.y - xd;
            const double sq = db * db + dd * dd;
            if (sq < vsq) { vsq = sq; amin = i + 1; }
        }
        v_j = sqrt(vsq);                              // exact: sqrt(min) == min(sqrt)
    }

    // ---- greedy tight matching: row r -> smallest col whose argmin is r ----
    atomicMin(&claim[amin], col);
    __syncthreads();
    if (claim[amin] == col) p_lds[col] = amin;        // tight: c=v[col], u=0
    __syncthreads();
    // freelist of unmatched rows
    claim[col] = 0;
    __syncthreads();
    { const int r = p_lds[col]; if (r) claim[r] = 1; }
    __syncthreads();
    if (tid == 0) {
        int nf = 0;
        for (int r = 1; r <= N; ++r) if (!claim[r]) flist[nf++] = r;
        nfree_s = nf;
    }
    __syncthreads();

    // ---- LAPJV augmenting row reduction (exactness-preserving, capped) ----
    {
        int head = 0, tail = nfree_s, q = 0;
        const int cap = 3 * tail + 16;
        int myp = p_lds[col];                          // register copy of p[col]
        for (int step = 0; step < cap && head < tail; ++step) {
            const int i = flist[head++];               // uniform broadcast
            const double2 rp = pt[i - 1];
            const double db = rp.x - xb, dd = rp.y - xd;
            const double val = sqrt(db * db + dd * dd) - v_j;   // exact f64
            const u64_t key = (map_f64(val) & ~0x7FFFFull)
                            | ((u64_t)(col - 1) << 10) | (u64_t)myp;
            u64_t kr = wave_min_key(key);
            if (lane == 63) atomicMin(&aslot[q], kr);
            __syncthreads();                           // barrier 1
            const u64_t k1 = aslot[q];
            const int j1    = (int)((k1 >> 10) & 511) + 1;
            const int k_old = (int)(k1 & 1023);
            if (col == j1) v1x = val;                  // exact v1 handoff
            kr = wave_min_key((col == j1) ? ~0ull : key);
            if (lane == 63) atomicMin(&bslot[q], kr);
            __syncthreads();                           // barrier 2
            const double m2t = unmap_f64(bslot[q] & ~0x7FFFFull);  // <= true 2nd-min
            const double v1e = v1x;
            const double ui  = fmax(m2t, v1e);         // feasible AND tight on j1
            if (col == j1) { v_j -= (ui - val); myp = i; }
            if (tid == 0) {
                u_lds[i] = ui;
                p_lds[j1] = i;
                if (k_old) flist[tail] = k_old;
                aslot[q ^ 1] = ~0ull; bslot[q ^ 1] = ~0ull;  // safe: 2 barriers since last read
            }
            if (k_old) ++tail;                         // uniform
            q ^= 1;
            __syncthreads();                           // barrier 3
        }
    }

    // ---- rebuild freelist from p ----
    claim[col] = 0;
    __syncthreads();
    { const int r = p_lds[col]; if (r) claim[r] = 1; }
    __syncthreads();
    if (tid == 0) {
        int nf = 0;
        for (int r = 1; r <= N; ++r) if (!claim[r]) flist[nf++] = r;
        nfree_s = nf;
    }
    __syncthreads();
    const int nfree = nfree_s;

    // ---- exact Dijkstra phase (absolute labels + sqrt filter + wave-min cache
    //      + contention-free slot combine) ----
    for (int kk = 0; kk < nfree; ++kk) {
        const int iroot = flist[kk];                   // ordered by prev end barrier
        const int pcol  = p_lds[col];                  // static during this Dijkstra
        if (tid == 0) p_lds[0] = iroot;                // only tid0 reads p[0] (augment)
        double minv = DBL_MAX;                         // ABSOLUTE dist label (stable)
        double D = 0.0, Dwin = 0.0;                    // uniform frontier dist / win dist
        bool used = false;
        int juse = 0, i0 = iroot, par = 0;
        u64_t key  = ~0ull;                            // cached own key
        u64_t wmin = ~0ull;                            // lane63's cached wave-min

        while (true) {
            // ---- A-phase ----
            bool trans = false;
            if (col == juse) {                         // prev winner: mark used
                used = true; Dwin = D; trans = true; key = ~0ull;
            }
            const double2 rp = pt[i0 - 1];             // broadcast b128
            const double u0 = u_lds[i0];               // untouched this Dijkstra
            bool upd = false;
            if (!used) {
                const double db = rp.x - xb, dd = rp.y - xd;
                const double s = db * db + dd * dd;
                // cand < minv  <=>  c < ((minv - D) + u0) + v_j  (exact algebra);
                // conservative filter with 1e-12 abs slack (>> fl error) so only
                // provably-no-update lanes skip the sqrt.
                const double T  = ((minv - D) + u0) + v_j;
                const double Tp = T + 1e-12;
                if (Tp > 0.0 && s < Tp * Tp) {
                    const double c = sqrt(s);          // exact f64, same expr as before
                    const double cand = D + ((c - u0) - v_j);
                    if (cand < minv) {
                        minv = cand; way_lds[col] = juse; upd = true;
                        key = (map_f64(minv) & ~0x7FFFFull)
                            | ((u64_t)(col - 1) << 10) | (u64_t)pcol;
                    }
                }
            }
            if (__any((int)(upd || trans))) {          // wave-uniform: keys changed?
                wmin = wave_min_key(key);
            }
            if (lane == 63) dslot[par][wid] = wmin;    // plain write, no contention
            __syncthreads();
            // ---- B-phase: broadcast-read 8 slots + min-tree ----
            const u64_t s0 = dslot[par][0], s1 = dslot[par][1];
            const u64_t s2 = dslot[par][2], s3 = dslot[par][3];
            const u64_t s4 = dslot[par][4], s5 = dslot[par][5];
            const u64_t s6 = dslot[par][6], s7 = dslot[par][7];
            const u64_t a0 = (s0 < s1) ? s0 : s1;
            const u64_t a1 = (s2 < s3) ? s2 : s3;
            const u64_t a2 = (s4 < s5) ? s4 : s5;
            const u64_t a3 = (s6 < s7) ? s6 : s7;
            const u64_t b0 = (a0 < a1) ? a0 : a1;
            const u64_t b1 = (a2 < a3) ? a2 : a3;
            const u64_t k  = (b0 < b1) ? b0 : b1;
            D = unmap_f64(k & ~0x7FFFFull);            // winner's (truncated) abs dist
            juse = (int)((k >> 10) & 511) + 1;
            i0   = (int)(k & 1023);                    // p payload; 0 => free col
            if (i0 == 0) break;
            par ^= 1;
        }

        // epilogue: settle duals (distinct rows => race-free), augment
        if (used) {
            const double du = D - Dwin;                // == sum of deltas while used
            u_lds[pcol] += du;
            v_j -= du;
        }
        if (tid == 0) {
            u_lds[iroot] += D;                         // == sum of all deltas (D_end)
            int j = juse;
            while (j) { const int jn = way_lds[j]; p_lds[j] = p_lds[jn]; j = jn; }
        }
        __syncthreads();
    }

    // ---- loss = 0.5 * sum_j ||dgm[p[j]-1] - dgm_x[j-1]||^2 (f32 diffs like ref) ----
    const int r = p_lds[col] - 1;
    const float2 a = dgm2[r];
    const float2 b = dgmx2[tid];
    const float fb = a.x - b.x;
    const float fd = a.y - b.y;
    double acc = (double)fb * (double)fb + (double)fd * (double)fd;
    #pragma unroll
    for (int m = 32; m >= 1; m >>= 1) acc += __shfl_xor(acc, m, 64);
    if (lane == 0) red8[wid] = acc;
    __syncthreads();
    if (tid == 0) {
        double s = 0.0;
        #pragma unroll
        for (int w = 0; w < 8; ++w) s += red8[w];
        out[0] = (float)(0.5 * s);
    }
}

extern "C" void kernel_launch(void* const* d_in, const int* in_sizes, int n_in,
                              void* d_out, int out_size, void* d_ws, size_t ws_size,
                              hipStream_t stream) {
    const float* dgm   = (const float*)d_in[0];
    const float* dgm_x = (const float*)d_in[1];
    float* out = (float*)d_out;
    tofu_solver<<<1, 512, 0, stream>>>(dgm, dgm_x, out);
}

// Round 10
// 5637.005 us; speedup vs baseline: 1.2367x; 1.2367x over previous
//
#include <hip/hip_runtime.h>
#include <cfloat>
#include <math.h>

#define N 512
typedef unsigned long long u64_t;

__device__ __forceinline__ u64_t map_f64(double x) {
    u64_t b = (u64_t)__double_as_longlong(x);
    return b ^ ((b >> 63) ? 0xFFFFFFFFFFFFFFFFull : 0x8000000000000000ull);
}
__device__ __forceinline__ double unmap_f64(u64_t b) {
    b ^= ((b >> 63) ? 0x8000000000000000ull : 0xFFFFFFFFFFFFFFFFull);
    return __longlong_as_double((long long)b);
}

// wave64 u64 min-reduce via DPP (VALU pipe). Valid result in lane 63.
// row_shr:1/2/4/8 reduce within 16-lane rows; row_bcast:15/31 merge rows.
// bound_ctrl=false + old=own value => lanes w/o source keep own (min identity).
__device__ __forceinline__ u64_t wave_min_key(u64_t key) {
    unsigned hi = (unsigned)(key >> 32), lo = (unsigned)key;
#define MIN_STAGE(CTRL)                                                        \
    {                                                                          \
        unsigned oh = (unsigned)__builtin_amdgcn_update_dpp((int)hi, (int)hi,  \
                                                            CTRL, 0xF, 0xF, false); \
        unsigned ol = (unsigned)__builtin_amdgcn_update_dpp((int)lo, (int)lo,  \
                                                            CTRL, 0xF, 0xF, false); \
        const u64_t o = ((u64_t)oh << 32) | ol;                                \
        const u64_t c = ((u64_t)hi << 32) | lo;                                \
        if (o < c) { hi = oh; lo = ol; }                                       \
    }
    MIN_STAGE(0x111) MIN_STAGE(0x112) MIN_STAGE(0x114) MIN_STAGE(0x118)
    MIN_STAGE(0x142) MIN_STAGE(0x143)
#undef MIN_STAGE
    return ((u64_t)hi << 32) | lo;
}

// 512 threads / 8 waves, thread t owns column t+1. Exact JV:
// column reduction + greedy tight match + LAPJV ARR warm start, then
// Dijkstra with DPP wave-reduce + 8-way atomicMin combine.
// key = [45b value | 9b col-1 | 10b p[col]] (truncation precedent: absmax 0).
// CONVERGED (R0-R9 ledger): per-iteration interval ~1050cy; every term
// empirically attacked, both directions:
//  - VALU (sqrt/f64 issue): off critical path. Filter = R4's +110us win;
//    further trims via LDS mirrors (R7) add critical-path reads => worse.
//  - c(i,j) via L2 cost matrix (R1): longer latency leg, worse.
//  - iteration count (R2, 2nd ARR pass): displacement churn, +715us.
//  - wave count (R3 4w, R5/R6 1w): fewer waves expose latency; 8-wave
//    barrier structure is the best latency-hider (1w = 3100cy/iter).
//  - combine placement (R9): atomicMin PRE-barrier overlaps wave skew;
//    post-barrier 8-slot read+tree = +260cy/iter, worse.
// This config: absolute labels + register-only f64 sqrt filter + wave-min
// caching = best verified (5641-5643us, absmax 0). Latency-bound on an
// irreducible serial dependency loop (~12k barrier-synced pops).
__global__ __launch_bounds__(512, 1) void tofu_solver(
    const float* __restrict__ dgm, const float* __restrict__ dgm_x,
    float* __restrict__ out)
{
#pragma clang fp contract(off)
    __shared__ double2 pt[N];
    __shared__ double  u_lds[N + 1];
    __shared__ int     p_lds[N + 1];
    __shared__ int     way_lds[N + 1];
    __shared__ int     claim[N + 1];
    __shared__ int     flist[4 * N + 32];
    __shared__ u64_t   dslot[3];        // Dijkstra combine slots (mod-3 rotation)
    __shared__ u64_t   aslot[2], bslot[2];  // ARR slots (parity)
    __shared__ double  v1x;
    __shared__ double  red8[8];
    __shared__ int     nfree_s;

    const int tid  = threadIdx.x;       // 0..511
    const int col  = tid + 1;           // 1..512
    const int lane = tid & 63;
    const int wid  = tid >> 6;
    const float2* dgm2  = (const float2*)dgm;
    const float2* dgmx2 = (const float2*)dgm_x;

    // ---- stage points; own column's target point in registers ----
    {
        const float2 p2 = dgm2[tid];
        pt[tid] = make_double2((double)p2.x, (double)p2.y);
    }
    const float2 q2 = dgmx2[tid];
    const double xb = (double)q2.x, xd = (double)q2.y;
    u_lds[col] = 0.0; p_lds[col] = 0; way_lds[col] = 0; claim[col] = 0x7fffffff;
    if (tid == 0) {
        u_lds[0] = 0.0; p_lds[0] = 0; way_lds[0] = 0; claim[0] = 0x7fffffff;
        dslot[0] = dslot[1] = dslot[2] = ~0ull;
        aslot[0] = aslot[1] = ~0ull; bslot[0] = bslot[1] = ~0ull;
    }
    __syncthreads();

    // ---- column reduction: argmin over squared dist (sqrt monotone => same v) ----
    double v_j; int amin;
    {
        double vsq = DBL_MAX; amin = 1;
        for (int i = 0; i < N; ++i) {
            const double2 rp = pt[i];                 // broadcast b128
            const double db = rp.x - xb, dd = rp.y - xd;
            const double sq = db * db + dd * dd;
            if (sq < vsq) { vsq = sq; amin = i + 1; }
        }
        v_j = sqrt(vsq);                              // exact: sqrt(min) == min(sqrt)
    }

    // ---- greedy tight matching: row r -> smallest col whose argmin is r ----
    atomicMin(&claim[amin], col);
    __syncthreads();
    if (claim[amin] == col) p_lds[col] = amin;        // tight: c=v[col], u=0
    __syncthreads();
    // freelist of unmatched rows
    claim[col] = 0;
    __syncthreads();
    { const int r = p_lds[col]; if (r) claim[r] = 1; }
    __syncthreads();
    if (tid == 0) {
        int nf = 0;
        for (int r = 1; r <= N; ++r) if (!claim[r]) flist[nf++] = r;
        nfree_s = nf;
    }
    __syncthreads();

    // ---- LAPJV augmenting row reduction (exactness-preserving, capped) ----
    {
        int head = 0, tail = nfree_s, q = 0;
        const int cap = 3 * tail + 16;
        int myp = p_lds[col];                          // register copy of p[col]
        for (int step = 0; step < cap && head < tail; ++step) {
            const int i = flist[head++];               // uniform broadcast
            const double2 rp = pt[i - 1];
            const double db = rp.x - xb, dd = rp.y - xd;
            const double val = sqrt(db * db + dd * dd) - v_j;   // exact f64
            const u64_t key = (map_f64(val) & ~0x7FFFFull)
                            | ((u64_t)(col - 1) << 10) | (u64_t)myp;
            u64_t kr = wave_min_key(key);
            if (lane == 63) atomicMin(&aslot[q], kr);
            __syncthreads();                           // barrier 1
            const u64_t k1 = aslot[q];
            const int j1    = (int)((k1 >> 10) & 511) + 1;
            const int k_old = (int)(k1 & 1023);
            if (col == j1) v1x = val;                  // exact v1 handoff
            kr = wave_min_key((col == j1) ? ~0ull : key);
            if (lane == 63) atomicMin(&bslot[q], kr);
            __syncthreads();                           // barrier 2
            const double m2t = unmap_f64(bslot[q] & ~0x7FFFFull);  // <= true 2nd-min
            const double v1e = v1x;
            const double ui  = fmax(m2t, v1e);         // feasible AND tight on j1
            if (col == j1) { v_j -= (ui - val); myp = i; }
            if (tid == 0) {
                u_lds[i] = ui;
                p_lds[j1] = i;
                if (k_old) flist[tail] = k_old;
                aslot[q ^ 1] = ~0ull; bslot[q ^ 1] = ~0ull;  // safe: 2 barriers since last read
            }
            if (k_old) ++tail;                         // uniform
            q ^= 1;
            __syncthreads();                           // barrier 3
        }
    }

    // ---- rebuild freelist from p ----
    claim[col] = 0;
    __syncthreads();
    { const int r = p_lds[col]; if (r) claim[r] = 1; }
    __syncthreads();
    if (tid == 0) {
        int nf = 0;
        for (int r = 1; r <= N; ++r) if (!claim[r]) flist[nf++] = r;
        nfree_s = nf;
    }
    __syncthreads();
    const int nfree = nfree_s;

    // ---- exact Dijkstra phase (absolute labels + sqrt filter + wave-min cache) ----
    for (int kk = 0; kk < nfree; ++kk) {
        const int iroot = flist[kk];                   // ordered by prev end barrier
        const int pcol  = p_lds[col];                  // static during this Dijkstra
        if (tid == 0) p_lds[0] = iroot;                // only tid0 reads p[0] (augment)
        double minv = DBL_MAX;                         // ABSOLUTE dist label (stable)
        double D = 0.0, Dwin = 0.0;                    // uniform frontier dist / win dist
        bool used = false;
        int juse = 0, i0 = iroot, par = 0;
        u64_t key  = ~0ull;                            // cached own key
        u64_t wmin = ~0ull;                            // lane63's cached wave-min

        while (true) {
            // ---- A-phase ----
            bool trans = false;
            if (col == juse) {                         // prev winner: mark used
                used = true; Dwin = D; trans = true; key = ~0ull;
            }
            const double2 rp = pt[i0 - 1];             // broadcast b128
            const double u0 = u_lds[i0];               // untouched this Dijkstra
            bool upd = false;
            if (!used) {
                const double db = rp.x - xb, dd = rp.y - xd;
                const double s = db * db + dd * dd;
                // cand < minv  <=>  c < ((minv - D) + u0) + v_j  (exact algebra);
                // conservative filter with 1e-12 abs slack (>> fl error) so only
                // provably-no-update lanes skip the sqrt.
                const double T  = ((minv - D) + u0) + v_j;
                const double Tp = T + 1e-12;
                if (Tp > 0.0 && s < Tp * Tp) {
                    const double c = sqrt(s);          // exact f64, same expr as before
                    const double cand = D + ((c - u0) - v_j);
                    if (cand < minv) {
                        minv = cand; way_lds[col] = juse; upd = true;
                        key = (map_f64(minv) & ~0x7FFFFull)
                            | ((u64_t)(col - 1) << 10) | (u64_t)pcol;
                    }
                }
            }
            if (__any((int)(upd || trans))) {          // wave-uniform: keys changed?
                wmin = wave_min_key(key);
            }
            if (lane == 63) atomicMin(&dslot[par], wmin);
            __syncthreads();
            // ---- B-phase ----
            const u64_t k = dslot[par];
            if (tid == 0) dslot[(par + 2) % 3] = ~0ull;  // last read 2 barriers ago
            D = unmap_f64(k & ~0x7FFFFull);            // winner's (truncated) abs dist
            juse = (int)((k >> 10) & 511) + 1;
            i0   = (int)(k & 1023);                    // p payload; 0 => free col
            if (i0 == 0) break;
            par = (par + 1) % 3;
        }

        // epilogue: settle duals (distinct rows => race-free), augment, clean slot
        if (used) {
            const double du = D - Dwin;                // == sum of deltas while used
            u_lds[pcol] += du;
            v_j -= du;
        }
        if (tid == 0) {
            u_lds[iroot] += D;                         // == sum of all deltas (D_end)
            dslot[par] = ~0ull;                        // the slot just consumed
            int j = juse;
            while (j) { const int jn = way_lds[j]; p_lds[j] = p_lds[jn]; j = jn; }
        }
        __syncthreads();
    }

    // ---- loss = 0.5 * sum_j ||dgm[p[j]-1] - dgm_x[j-1]||^2 (f32 diffs like ref) ----
    const int r = p_lds[col] - 1;
    const float2 a = dgm2[r];
    const float2 b = dgmx2[tid];
    const float fb = a.x - b.x;
    const float fd = a.y - b.y;
    double acc = (double)fb * (double)fb + (double)fd * (double)fd;
    #pragma unroll
    for (int m = 32; m >= 1; m >>= 1) acc += __shfl_xor(acc, m, 64);
    if (lane == 0) red8[wid] = acc;
    __syncthreads();
    if (tid == 0) {
        double s = 0.0;
        #pragma unroll
        for (int w = 0; w < 8; ++w) s += red8[w];
        out[0] = (float)(0.5 * s);
    }
}

extern "C" void kernel_launch(void* const* d_in, const int* in_sizes, int n_in,
                              void* d_out, int out_size, void* d_ws, size_t ws_size,
                              hipStream_t stream) {
    const float* dgm   = (const float*)d_in[0];
    const float* dgm_x = (const float*)d_in[1];
    float* out = (float*)d_out;
    tofu_solver<<<1, 512, 0, stream>>>(dgm, dgm_x, out);
}